// Round 9
// baseline (280.337 us; speedup 1.0000x reference)
//
#include <hip/hip_runtime.h>
#include <hip/hip_bf16.h>

typedef unsigned int uint;
typedef _Float16 f16;
typedef _Float16 f16x8 __attribute__((ext_vector_type(8)));
typedef float f32x4 __attribute__((ext_vector_type(4)));

#define T_STEPS 100

// ---------------- ws layout (bytes), with overlays ----------------
#define OFF_H1    (size_t)0
#define OFF_WHI   (size_t)0            // conv2 packs overlay dead h1
#define OFF_WLO   (size_t)73728
#define OFF_P1    (size_t)3211264      // ends 29,425,664
#define OFF_H2    (size_t)29425664     // 80,281,600; dead after lif2pool; overlays below
#define OFF_H3    (size_t)29425664     //   6,553,600
#define OFF_S3    (size_t)35979264     //   1,638,400
#define OFF_H4    (size_t)37617664     //      64,000
#define OFF_WF1L  (size_t)37681664     //   6,422,528 (packed after lif2pool)
#define OFF_WF1H  (size_t)44104192     //   6,422,528 (ends 50,526,720 < h2 end)
#define OFF_P2H   (size_t)109707264    //  10,035,200 f16 spikes (ends 119,742,464)

__device__ __forceinline__ int lif_step_i(float& v, float x) {
  v = __fadd_rn(v, __fmul_rn(__fsub_rn(x, v), 0.5f));
  if (v >= 1.0f) { v = 0.0f; return 1; }
  return 0;
}

// ---------------- conv2 weight prep: fragment-major fp16 hi/lo split ----------------
__global__ __launch_bounds__(256) void k_prep_w2(const float* __restrict__ w2,
                                                 f16* __restrict__ whi, f16* __restrict__ wlo) {
  int i = blockIdx.x * 256 + threadIdx.x;       // < 36864
  int j = i & 7, l = (i >> 3) & 63, cb = (i >> 9) & 3, kb = i >> 11;
  int k = kb * 32 + (l >> 4) * 8 + j;
  int co = cb * 16 + (l & 15);
  int ci = k & 63, tap = k >> 6;
  int dy = tap / 3, dx = tap - 3 * dy;
  float w = w2[((co * 64 + ci) * 3 + dy) * 3 + dx];
  float hif = (fabsf(w) < 6.104e-5f) ? 0.0f : (float)(f16)w;
  whi[i] = (f16)hif;
  wlo[i] = (f16)((w - hif) * 4096.0f);
}

// ---------------- fc1 weight prep: fragment-major fp16 hi/lo split ----------------
__global__ __launch_bounds__(256) void k_prep_wfc1(const float* __restrict__ wfc1,
                                                   f16* __restrict__ whi, f16* __restrict__ wlo) {
  int i = blockIdx.x * 256 + threadIdx.x;       // < 3,211,264
  int j = i & 7, lane = (i >> 3) & 63;
  int rest = i >> 9;
  int oblk = rest & 63, kbG = rest >> 6;        // kbG < 98
  int o = oblk * 16 + (lane & 15);
  int k = kbG * 32 + (lane >> 4) * 8 + j;
  float w = wfc1[(size_t)o * 3136 + k];
  float hif = (fabsf(w) < 6.104e-5f) ? 0.0f : (float)(f16)w;
  whi[i] = (f16)hif;
  wlo[i] = (f16)((w - hif) * 4096.0f);
}

__global__ __launch_bounds__(256) void k_zero_h3(float4* __restrict__ p) {
  p[blockIdx.x * 256 + threadIdx.x] = make_float4(0.f, 0.f, 0.f, 0.f);
}

// ---------------- conv1 + BN1 ----------------
__global__ __launch_bounds__(256) void k_conv1(const float* __restrict__ x, const float* __restrict__ w1,
                                               const float* __restrict__ g1, const float* __restrict__ b1,
                                               const float* __restrict__ m1, const float* __restrict__ v1,
                                               float* __restrict__ h1) {
  int i = blockIdx.x * 256 + threadIdx.x;      // < 802816
  int pos = i % 784;
  int bc  = i / 784;
  int c = bc & 63, b = bc >> 6;
  int y = pos / 28, xx = pos % 28;
  float a = 0.f;
#pragma unroll
  for (int dy = 0; dy < 3; ++dy) {
    int iy = y + dy - 1;
#pragma unroll
    for (int dx = 0; dx < 3; ++dx) {
      int ix = xx + dx - 1;
      if (iy >= 0 && iy < 28 && ix >= 0 && ix < 28)
        a = fmaf(w1[c * 9 + dy * 3 + dx], x[b * 784 + iy * 28 + ix], a);
    }
  }
  float inv  = g1[c] / sqrtf(v1[c] + 1e-5f);
  float bias = __fsub_rn(b1[c], __fmul_rn(m1[c], inv));
  h1[i] = __fadd_rn(__fmul_rn(a, inv), bias);
}

// ---------------- LIF1 + maxpool -> p1 (u8, channels-last halo [pix][ci]) ----------------
__global__ __launch_bounds__(256) void k_lif1pool(const float* __restrict__ h1,
                                                  unsigned char* __restrict__ p1) {
  int t = blockIdx.x * 256 + threadIdx.x;      // < 262144
  int ci = t & 63, xx = (t >> 6) & 15, y = (t >> 10) & 15, b = t >> 14;
  int pix = y * 16 + xx;
  size_t outbase = (size_t)b * 16384 + pix * 64 + ci;
  const size_t tstride = (size_t)16 * 16384;
  if (y == 0 || y == 15 || xx == 0 || xx == 15) {
    for (int tt = 0; tt < T_STEPS; ++tt) p1[outbase + (size_t)tt * tstride] = 0;
    return;
  }
  int py = y - 1, px = xx - 1;
  const float* hp = h1 + ((size_t)(b * 64 + ci) * 28 + 2 * py) * 28 + 2 * px;
  float h00 = hp[0], h01 = hp[1], h10 = hp[28], h11 = hp[29];
  float v00 = 0.f, v01 = 0.f, v10 = 0.f, v11 = 0.f;
  for (int tt = 0; tt < T_STEPS; ++tt) {
    int s = 0;
    s |= lif_step_i(v00, h00);
    s |= lif_step_i(v01, h01);
    s |= lif_step_i(v10, h10);
    s |= lif_step_i(v11, h11);
    p1[outbase + (size_t)tt * tstride] = (unsigned char)s;
  }
}

// ---------------- conv2 + BN2 via MFMA, kb-outer / oy-inner (weights in regs) ----------------
__global__ __launch_bounds__(256, 2) void k_conv2(const unsigned char* __restrict__ p1,
                                                  const f16* __restrict__ whi, const f16* __restrict__ wlo,
                                                  const float* __restrict__ g2, const float* __restrict__ b2,
                                                  const float* __restrict__ m2, const float* __restrict__ v2,
                                                  float* __restrict__ h2) {
  __shared__ unsigned char smem[33024];        // 258 rows * 128B, XOR-swizzled
  const int tid = threadIdx.x;
  const int tb = blockIdx.x;
  const unsigned char* img = p1 + (size_t)tb * 16384;
#pragma unroll
  for (int it = 0; it < 4; ++it) {
    int s = it * 256 + tid;
    uint4 d = *(const uint4*)(img + (size_t)s * 16);
    int pix = s >> 2, c4 = s & 3;
    uint dw[4] = {d.x, d.y, d.z, d.w};
    f16x8 va, vb;
#pragma unroll
    for (int e = 0; e < 8; ++e) {
      va[e] = (f16)(float)((dw[e >> 2] >> ((e & 3) * 8)) & 255u);
      vb[e] = (f16)(float)((dw[2 + (e >> 2)] >> ((e & 3) * 8)) & 255u);
    }
    int rowbase = pix * 128;
    int sw = (pix & 7) << 4;
    *(f16x8*)(smem + rowbase + ((c4 * 32) ^ sw)) = va;
    *(f16x8*)(smem + rowbase + ((c4 * 32 + 16) ^ sw)) = vb;
  }
  if (tid < 16) *(uint4*)(smem + 32768 + tid * 16) = make_uint4(0u, 0u, 0u, 0u);
  __syncthreads();

  const int lane = tid & 63;
  const int wave = tid >> 6;
  const int ox = lane & 15;
  const int g = lane >> 4;
  const int cohalf = wave & 1;
  const int pb0 = (wave >> 1) * 7;

  f32x4 aH0[7], aL0[7], aH1[7], aL1[7];
#pragma unroll
  for (int q = 0; q < 7; ++q) {
    aH0[q] = (f32x4){0.f, 0.f, 0.f, 0.f};
    aL0[q] = (f32x4){0.f, 0.f, 0.f, 0.f};
    aH1[q] = (f32x4){0.f, 0.f, 0.f, 0.f};
    aL1[q] = (f32x4){0.f, 0.f, 0.f, 0.f};
  }

#pragma unroll 2
  for (int kb = 0; kb < 18; ++kb) {
    const int tap = kb >> 1;
    const int dy = tap / 3, dx = tap - 3 * dy;
    const int cilo2 = (kb & 1) * 64;
    size_t abase = ((size_t)(kb * 4 + cohalf * 2) * 64 + lane) * 8;
    f16x8 ah0 = *(const f16x8*)(whi + abase);
    f16x8 al0 = *(const f16x8*)(wlo + abase);
    f16x8 ah1 = *(const f16x8*)(whi + abase + 512);
    f16x8 al1 = *(const f16x8*)(wlo + abase + 512);
#pragma unroll
    for (int q = 0; q < 7; ++q) {
      int pix = (pb0 + q + dy) * 16 + ox + dx;
      int boff = pix * 128 + ((cilo2 + g * 16) ^ ((pix & 7) << 4));
      f16x8 bf = *(const f16x8*)(smem + boff);
      aH0[q] = __builtin_amdgcn_mfma_f32_16x16x32_f16(ah0, bf, aH0[q], 0, 0, 0);
      aL0[q] = __builtin_amdgcn_mfma_f32_16x16x32_f16(al0, bf, aL0[q], 0, 0, 0);
      aH1[q] = __builtin_amdgcn_mfma_f32_16x16x32_f16(ah1, bf, aH1[q], 0, 0, 0);
      aL1[q] = __builtin_amdgcn_mfma_f32_16x16x32_f16(al1, bf, aL1[q], 0, 0, 0);
    }
  }

  float binv[2][4], bofs[2][4];
#pragma unroll
  for (int cb = 0; cb < 2; ++cb)
#pragma unroll
    for (int r = 0; r < 4; ++r) {
      int co = (cohalf * 2 + cb) * 16 + g * 4 + r;
      float iv = g2[co] / sqrtf(v2[co] + 1e-5f);
      binv[cb][r] = iv;
      bofs[cb][r] = __fsub_rn(b2[co], __fmul_rn(m2[co], iv));
    }

  if (ox < 14) {
#pragma unroll
    for (int q = 0; q < 7; ++q) {
      int oy = pb0 + q;
#pragma unroll
      for (int r = 0; r < 4; ++r) {
        int co0 = cohalf * 32 + g * 4 + r;
        float s0 = __fadd_rn(aH0[q][r], __fmul_rn(aL0[q][r], 1.0f / 4096.0f));
        h2[((size_t)tb * 64 + co0) * 196 + oy * 14 + ox] =
            __fadd_rn(__fmul_rn(s0, binv[0][r]), bofs[0][r]);
        int co1 = co0 + 16;
        float s1 = __fadd_rn(aH1[q][r], __fmul_rn(aL1[q][r], 1.0f / 4096.0f));
        h2[((size_t)tb * 64 + co1) * 196 + oy * 14 + ox] =
            __fadd_rn(__fmul_rn(s1, binv[1][r]), bofs[1][r]);
      }
    }
  }
}

// ---------------- LIF2 + maxpool -> p2h (f16 spikes, exact) ----------------
__global__ __launch_bounds__(256) void k_lif2pool(const float* __restrict__ h2,
                                                  f16* __restrict__ p2h) {
  int t = blockIdx.x * 256 + threadIdx.x;      // < 50176
  int px = t % 7;
  int r1 = t / 7;
  int py = r1 % 7;
  int r2 = r1 / 7;
  int c = r2 & 63, b = r2 >> 6;
  const float* base = h2 + ((size_t)b * 64 + c) * 196 + (2 * py) * 14 + 2 * px;
  const size_t tstride = (size_t)16 * 64 * 196;
  f16* op = p2h + (size_t)b * 3136 + c * 49 + py * 7 + px;
  const size_t otstride = (size_t)16 * 3136;
  float v00 = 0.f, v01 = 0.f, v10 = 0.f, v11 = 0.f;
#pragma unroll 4
  for (int tt = 0; tt < T_STEPS; ++tt) {
    const float* hp = base + (size_t)tt * tstride;
    float2 r0 = *(const float2*)(hp);
    float2 r1v = *(const float2*)(hp + 14);
    int s = 0;
    s |= lif_step_i(v00, r0.x);
    s |= lif_step_i(v01, r0.y);
    s |= lif_step_i(v10, r1v.x);
    s |= lif_step_i(v11, r1v.y);
    op[(size_t)tt * otstride] = (f16)s;
  }
}

// ---------------- FC1 via MFMA (fp16 hi/lo), split-K=2, pipelined, XCD-grouped ----------------
// 1D grid 416 = 8 xcd * (4 slices * 13 tb-blocks). slice s=(yb,z); all 13 tb-blocks of a
// slice land on one XCD (bid%8 = s%8) -> weight slice stays in that XCD's L2.
__global__ __launch_bounds__(256, 3) void k_fc1(const f16* __restrict__ p2h,
                                                const f16* __restrict__ whi, const f16* __restrict__ wlo,
                                                float* __restrict__ h3) {
  __shared__ unsigned char bsm[2][128 * 80];   // f16 [tb][32k], row 80B (5x16B -> <=2-way)
  const int tid = threadIdx.x;
  const int lane = tid & 63;
  const int wave = tid >> 6;
  int bid = blockIdx.x;
  int k8 = bid & 7, j = bid >> 3;              // j < 52
  int sh = j / 13, xb = j - sh * 13;           // sh<4, xb<13
  int s = k8 + 8 * sh;                         // slice < 32
  int yb = s >> 1, z = s & 1;
  const int tb0 = xb * 128;
  const int oblk = yb * 4 + wave;              // o-16-block
  const int tbl = tid >> 1, half = tid & 1;    // staging role: 32B per thread
  const int stb = tb0 + tbl;
  const bool sok = (stb < 1600);
  const uint4* spq = (const uint4*)(p2h + (size_t)stb * 3136 + z * 1568 + half * 16);

  f32x4 accH[8], accL[8];
#pragma unroll
  for (int n = 0; n < 8; ++n) {
    accH[n] = (f32x4){0.f, 0.f, 0.f, 0.f};
    accL[n] = (f32x4){0.f, 0.f, 0.f, 0.f};
  }

  const int kbG0 = z * 49;
  size_t afrag = ((size_t)(kbG0 * 64 + oblk) * 64 + lane) * 8;
  const size_t astep = (size_t)64 * 64 * 8;    // elements per kbG
  f16x8 ahC = *(const f16x8*)(whi + afrag);
  f16x8 alC = *(const f16x8*)(wlo + afrag);
  const uint4 z4 = make_uint4(0u, 0u, 0u, 0u);
  uint4 dA = sok ? spq[0] : z4;
  uint4 dB = sok ? spq[1] : z4;

  for (int kb = 0; kb < 49; ++kb) {
    // prefetch next iteration's B tile + A frags (hides global latency under MFMA)
    uint4 nA = z4, nB = z4;
    f16x8 ahN = ahC, alN = alC;
    if (kb < 48) {
      if (sok) { nA = spq[kb * 4 + 4]; nB = spq[kb * 4 + 5]; }
      ahN = *(const f16x8*)(whi + afrag + (size_t)(kb + 1) * astep);
      alN = *(const f16x8*)(wlo + afrag + (size_t)(kb + 1) * astep);
    }
    unsigned char* row = &bsm[kb & 1][tbl * 80 + half * 32];
    *(uint4*)(row) = dA;
    *(uint4*)(row + 16) = dB;
    __syncthreads();
    const unsigned char* buf = &bsm[kb & 1][0];
#pragma unroll
    for (int n = 0; n < 8; ++n) {
      f16x8 bf = *(const f16x8*)(buf + (n * 16 + (lane & 15)) * 80 + (lane >> 4) * 16);
      accH[n] = __builtin_amdgcn_mfma_f32_16x16x32_f16(ahC, bf, accH[n], 0, 0, 0);
      accL[n] = __builtin_amdgcn_mfma_f32_16x16x32_f16(alC, bf, accL[n], 0, 0, 0);
    }
    dA = nA; dB = nB; ahC = ahN; alC = alN;
  }

  const int o = yb * 64 + wave * 16 + (lane >> 4) * 4;
#pragma unroll
  for (int n = 0; n < 8; ++n) {
    int tb = tb0 + n * 16 + (lane & 15);
    if (tb < 1600) {
      float* hp = h3 + (size_t)tb * 1024 + o;
#pragma unroll
      for (int r = 0; r < 4; ++r) {
        float sv = __fadd_rn(accH[n][r], __fmul_rn(accL[n][r], 1.0f / 4096.0f));
        atomicAdd(hp + r, sv);
      }
    }
  }
}

// ---------------- LIF3 -> s3 (u8) ----------------
__global__ __launch_bounds__(256) void k_lif3(const float* __restrict__ h3,
                                              unsigned char* __restrict__ s3) {
  int t = blockIdx.x * 256 + threadIdx.x;      // < 16384
  int o = t & 1023, b = t >> 10;
  size_t base = (size_t)b * 1024 + o;
  float v = 0.f;
#pragma unroll 10
  for (int tt = 0; tt < T_STEPS; ++tt) {
    float xv = h3[base + (size_t)tt * 16384];
    s3[base + (size_t)tt * 16384] = (unsigned char)lif_step_i(v, xv);
  }
}

// ---------------- FC2 ----------------
__global__ __launch_bounds__(64) void k_fc2(const unsigned char* __restrict__ s3,
                                            const float* __restrict__ wfc2,
                                            float* __restrict__ h4) {
  int tb = blockIdx.x;                          // < 1600
  int l = threadIdx.x;
  const unsigned char* srow = s3 + (size_t)tb * 1024;
  float p[10];
#pragma unroll
  for (int o = 0; o < 10; ++o) p[o] = 0.f;
  for (int j = 0; j < 16; ++j) {
    int k = l + j * 64;
    float s = (float)srow[k];
#pragma unroll
    for (int o = 0; o < 10; ++o)
      p[o] = fmaf(s, wfc2[o * 1024 + k], p[o]);
  }
#pragma unroll
  for (int o = 0; o < 10; ++o) {
    float v = p[o];
    for (int off = 32; off > 0; off >>= 1) v += __shfl_down(v, off, 64);
    if (l == 0) h4[(size_t)tb * 10 + o] = v;
  }
}

// ---------------- LIF4 + mean ----------------
__global__ __launch_bounds__(256) void k_lif4mean(const float* __restrict__ h4,
                                                  float* __restrict__ out) {
  int t = threadIdx.x;
  if (t >= 160) return;
  int o = t % 10, b = t / 10;
  float v = 0.f;
  int cnt = 0;
#pragma unroll 10
  for (int tt = 0; tt < T_STEPS; ++tt) {
    float xv = h4[(size_t)tt * 160 + b * 10 + o];
    cnt += lif_step_i(v, xv);
  }
  out[b * 10 + o] = (float)cnt / 100.0f;
}

extern "C" void kernel_launch(void* const* d_in, const int* in_sizes, int n_in,
                              void* d_out, int out_size, void* d_ws, size_t ws_size,
                              hipStream_t stream) {
  const float* x    = (const float*)d_in[0];
  const float* W1   = (const float*)d_in[1];
  const float* g1   = (const float*)d_in[2];
  const float* b1   = (const float*)d_in[3];
  const float* m1   = (const float*)d_in[4];
  const float* v1   = (const float*)d_in[5];
  const float* W2   = (const float*)d_in[6];
  const float* g2   = (const float*)d_in[7];
  const float* b2   = (const float*)d_in[8];
  const float* m2   = (const float*)d_in[9];
  const float* v2   = (const float*)d_in[10];
  const float* Wfc1 = (const float*)d_in[11];
  const float* Wfc2 = (const float*)d_in[12];
  float* out = (float*)d_out;
  char* ws = (char*)d_ws;

  float*         h1   = (float*)(ws + OFF_H1);
  f16*           whi  = (f16*)(ws + OFF_WHI);
  f16*           wlo  = (f16*)(ws + OFF_WLO);
  unsigned char* p1   = (unsigned char*)(ws + OFF_P1);
  float*         h2   = (float*)(ws + OFF_H2);
  f16*           p2h  = (f16*)(ws + OFF_P2H);
  float*         h3   = (float*)(ws + OFF_H3);
  unsigned char* s3   = (unsigned char*)(ws + OFF_S3);
  float*         h4   = (float*)(ws + OFF_H4);
  f16*           wf1h = (f16*)(ws + OFF_WF1H);
  f16*           wf1l = (f16*)(ws + OFF_WF1L);

  k_conv1<<<3136, 256, 0, stream>>>(x, W1, g1, b1, m1, v1, h1);
  k_lif1pool<<<1024, 256, 0, stream>>>(h1, p1);
  k_prep_w2<<<144, 256, 0, stream>>>(W2, whi, wlo);        // overlays dead h1
  k_conv2<<<1600, 256, 0, stream>>>(p1, whi, wlo, g2, b2, m2, v2, h2);
  k_lif2pool<<<196, 256, 0, stream>>>(h2, p2h);
  k_prep_wfc1<<<12544, 256, 0, stream>>>(Wfc1, wf1h, wf1l); // overlays dead h2
  k_zero_h3<<<1600, 256, 0, stream>>>((float4*)h3);
  k_fc1<<<416, 256, 0, stream>>>(p2h, wf1h, wf1l, h3);
  k_lif3<<<64, 256, 0, stream>>>(h3, s3);
  k_fc2<<<1600, 64, 0, stream>>>(s3, Wfc2, h4);
  k_lif4mean<<<1, 256, 0, stream>>>(h4, out);
}

// Round 11
// 231.163 us; speedup vs baseline: 1.2127x; 1.2127x over previous
//
#include <hip/hip_runtime.h>
#include <hip/hip_bf16.h>

typedef unsigned int uint;
typedef _Float16 f16;
typedef _Float16 f16x8 __attribute__((ext_vector_type(8)));
typedef float f32x4 __attribute__((ext_vector_type(4)));

#define T_STEPS 100

// ---------------- ws layout (bytes), with overlays ----------------
#define OFF_H1    (size_t)0
#define OFF_WHI   (size_t)0            // conv2 packs overlay dead h1
#define OFF_WLO   (size_t)73728
#define OFF_P1    (size_t)3211264      // ends 29,425,664
#define OFF_H2    (size_t)29425664     // 80,281,600; dead after lif2pool; overlays below
#define OFF_H3A   (size_t)29425664     //   6,553,600
#define OFF_H3B   (size_t)35979264     //   6,553,600
#define OFF_S3    (size_t)42532864     //   1,638,400
#define OFF_H4    (size_t)44171264     //      64,000
#define OFF_WF1L  (size_t)44235264     //   6,422,528
#define OFF_WF1H  (size_t)50657792     //   6,422,528 (ends 57,080,320 < h2 end)
#define OFF_P2H   (size_t)109707264    //  10,035,200 f16 spikes (ends 119,742,464)

__device__ __forceinline__ int lif_step_i(float& v, float x) {
  v = __fadd_rn(v, __fmul_rn(__fsub_rn(x, v), 0.5f));
  if (v >= 1.0f) { v = 0.0f; return 1; }
  return 0;
}

// ---------------- conv2 weight prep: fragment-major fp16 hi/lo split ----------------
__global__ __launch_bounds__(256) void k_prep_w2(const float* __restrict__ w2,
                                                 f16* __restrict__ whi, f16* __restrict__ wlo) {
  int i = blockIdx.x * 256 + threadIdx.x;       // < 36864
  int j = i & 7, l = (i >> 3) & 63, cb = (i >> 9) & 3, kb = i >> 11;
  int k = kb * 32 + (l >> 4) * 8 + j;
  int co = cb * 16 + (l & 15);
  int ci = k & 63, tap = k >> 6;
  int dy = tap / 3, dx = tap - 3 * dy;
  float w = w2[((co * 64 + ci) * 3 + dy) * 3 + dx];
  float hif = (fabsf(w) < 6.104e-5f) ? 0.0f : (float)(f16)w;
  whi[i] = (f16)hif;
  wlo[i] = (f16)((w - hif) * 4096.0f);
}

// ---------------- fc1 weight prep: fragment-major fp16 hi/lo split ----------------
__global__ __launch_bounds__(256) void k_prep_wfc1(const float* __restrict__ wfc1,
                                                   f16* __restrict__ whi, f16* __restrict__ wlo) {
  int i = blockIdx.x * 256 + threadIdx.x;       // < 3,211,264
  int j = i & 7, lane = (i >> 3) & 63;
  int rest = i >> 9;
  int oblk = rest & 63, kbG = rest >> 6;        // kbG < 98
  int o = oblk * 16 + (lane & 15);
  int k = kbG * 32 + (lane >> 4) * 8 + j;
  float w = wfc1[(size_t)o * 3136 + k];
  float hif = (fabsf(w) < 6.104e-5f) ? 0.0f : (float)(f16)w;
  whi[i] = (f16)hif;
  wlo[i] = (f16)((w - hif) * 4096.0f);
}

// ---------------- conv1 + BN1 ----------------
__global__ __launch_bounds__(256) void k_conv1(const float* __restrict__ x, const float* __restrict__ w1,
                                               const float* __restrict__ g1, const float* __restrict__ b1,
                                               const float* __restrict__ m1, const float* __restrict__ v1,
                                               float* __restrict__ h1) {
  int i = blockIdx.x * 256 + threadIdx.x;      // < 802816
  int pos = i % 784;
  int bc  = i / 784;
  int c = bc & 63, b = bc >> 6;
  int y = pos / 28, xx = pos % 28;
  float a = 0.f;
#pragma unroll
  for (int dy = 0; dy < 3; ++dy) {
    int iy = y + dy - 1;
#pragma unroll
    for (int dx = 0; dx < 3; ++dx) {
      int ix = xx + dx - 1;
      if (iy >= 0 && iy < 28 && ix >= 0 && ix < 28)
        a = fmaf(w1[c * 9 + dy * 3 + dx], x[b * 784 + iy * 28 + ix], a);
    }
  }
  float inv  = g1[c] / sqrtf(v1[c] + 1e-5f);
  float bias = __fsub_rn(b1[c], __fmul_rn(m1[c], inv));
  h1[i] = __fadd_rn(__fmul_rn(a, inv), bias);
}

// ---------------- LIF1 + maxpool -> p1 (u8, channels-last halo [pix][ci]) ----------------
__global__ __launch_bounds__(256) void k_lif1pool(const float* __restrict__ h1,
                                                  unsigned char* __restrict__ p1) {
  int t = blockIdx.x * 256 + threadIdx.x;      // < 262144
  int ci = t & 63, xx = (t >> 6) & 15, y = (t >> 10) & 15, b = t >> 14;
  int pix = y * 16 + xx;
  size_t outbase = (size_t)b * 16384 + pix * 64 + ci;
  const size_t tstride = (size_t)16 * 16384;
  if (y == 0 || y == 15 || xx == 0 || xx == 15) {
    for (int tt = 0; tt < T_STEPS; ++tt) p1[outbase + (size_t)tt * tstride] = 0;
    return;
  }
  int py = y - 1, px = xx - 1;
  const float* hp = h1 + ((size_t)(b * 64 + ci) * 28 + 2 * py) * 28 + 2 * px;
  float h00 = hp[0], h01 = hp[1], h10 = hp[28], h11 = hp[29];
  float v00 = 0.f, v01 = 0.f, v10 = 0.f, v11 = 0.f;
  for (int tt = 0; tt < T_STEPS; ++tt) {
    int s = 0;
    s |= lif_step_i(v00, h00);
    s |= lif_step_i(v01, h01);
    s |= lif_step_i(v10, h10);
    s |= lif_step_i(v11, h11);
    p1[outbase + (size_t)tt * tstride] = (unsigned char)s;
  }
}

// ---------------- conv2 + BN2 via MFMA, kb-outer / oy-inner (weights in regs) ----------------
__global__ __launch_bounds__(256, 2) void k_conv2(const unsigned char* __restrict__ p1,
                                                  const f16* __restrict__ whi, const f16* __restrict__ wlo,
                                                  const float* __restrict__ g2, const float* __restrict__ b2,
                                                  const float* __restrict__ m2, const float* __restrict__ v2,
                                                  float* __restrict__ h2) {
  __shared__ unsigned char smem[33024];        // 258 rows * 128B, XOR-swizzled
  const int tid = threadIdx.x;
  const int tb = blockIdx.x;
  const unsigned char* img = p1 + (size_t)tb * 16384;
#pragma unroll
  for (int it = 0; it < 4; ++it) {
    int s = it * 256 + tid;
    uint4 d = *(const uint4*)(img + (size_t)s * 16);
    int pix = s >> 2, c4 = s & 3;
    uint dw[4] = {d.x, d.y, d.z, d.w};
    f16x8 va, vb;
#pragma unroll
    for (int e = 0; e < 8; ++e) {
      va[e] = (f16)(float)((dw[e >> 2] >> ((e & 3) * 8)) & 255u);
      vb[e] = (f16)(float)((dw[2 + (e >> 2)] >> ((e & 3) * 8)) & 255u);
    }
    int rowbase = pix * 128;
    int sw = (pix & 7) << 4;
    *(f16x8*)(smem + rowbase + ((c4 * 32) ^ sw)) = va;
    *(f16x8*)(smem + rowbase + ((c4 * 32 + 16) ^ sw)) = vb;
  }
  if (tid < 16) *(uint4*)(smem + 32768 + tid * 16) = make_uint4(0u, 0u, 0u, 0u);
  __syncthreads();

  const int lane = tid & 63;
  const int wave = tid >> 6;
  const int ox = lane & 15;
  const int g = lane >> 4;
  const int cohalf = wave & 1;
  const int pb0 = (wave >> 1) * 7;

  f32x4 aH0[7], aL0[7], aH1[7], aL1[7];
#pragma unroll
  for (int q = 0; q < 7; ++q) {
    aH0[q] = (f32x4){0.f, 0.f, 0.f, 0.f};
    aL0[q] = (f32x4){0.f, 0.f, 0.f, 0.f};
    aH1[q] = (f32x4){0.f, 0.f, 0.f, 0.f};
    aL1[q] = (f32x4){0.f, 0.f, 0.f, 0.f};
  }

#pragma unroll 2
  for (int kb = 0; kb < 18; ++kb) {
    const int tap = kb >> 1;
    const int dy = tap / 3, dx = tap - 3 * dy;
    const int cilo2 = (kb & 1) * 64;
    size_t abase = ((size_t)(kb * 4 + cohalf * 2) * 64 + lane) * 8;
    f16x8 ah0 = *(const f16x8*)(whi + abase);
    f16x8 al0 = *(const f16x8*)(wlo + abase);
    f16x8 ah1 = *(const f16x8*)(whi + abase + 512);
    f16x8 al1 = *(const f16x8*)(wlo + abase + 512);
#pragma unroll
    for (int q = 0; q < 7; ++q) {
      int pix = (pb0 + q + dy) * 16 + ox + dx;
      int boff = pix * 128 + ((cilo2 + g * 16) ^ ((pix & 7) << 4));
      f16x8 bf = *(const f16x8*)(smem + boff);
      aH0[q] = __builtin_amdgcn_mfma_f32_16x16x32_f16(ah0, bf, aH0[q], 0, 0, 0);
      aL0[q] = __builtin_amdgcn_mfma_f32_16x16x32_f16(al0, bf, aL0[q], 0, 0, 0);
      aH1[q] = __builtin_amdgcn_mfma_f32_16x16x32_f16(ah1, bf, aH1[q], 0, 0, 0);
      aL1[q] = __builtin_amdgcn_mfma_f32_16x16x32_f16(al1, bf, aL1[q], 0, 0, 0);
    }
  }

  float binv[2][4], bofs[2][4];
#pragma unroll
  for (int cb = 0; cb < 2; ++cb)
#pragma unroll
    for (int r = 0; r < 4; ++r) {
      int co = (cohalf * 2 + cb) * 16 + g * 4 + r;
      float iv = g2[co] / sqrtf(v2[co] + 1e-5f);
      binv[cb][r] = iv;
      bofs[cb][r] = __fsub_rn(b2[co], __fmul_rn(m2[co], iv));
    }

  if (ox < 14) {
#pragma unroll
    for (int q = 0; q < 7; ++q) {
      int oy = pb0 + q;
#pragma unroll
      for (int r = 0; r < 4; ++r) {
        int co0 = cohalf * 32 + g * 4 + r;
        float s0 = __fadd_rn(aH0[q][r], __fmul_rn(aL0[q][r], 1.0f / 4096.0f));
        h2[((size_t)tb * 64 + co0) * 196 + oy * 14 + ox] =
            __fadd_rn(__fmul_rn(s0, binv[0][r]), bofs[0][r]);
        int co1 = co0 + 16;
        float s1 = __fadd_rn(aH1[q][r], __fmul_rn(aL1[q][r], 1.0f / 4096.0f));
        h2[((size_t)tb * 64 + co1) * 196 + oy * 14 + ox] =
            __fadd_rn(__fmul_rn(s1, binv[1][r]), bofs[1][r]);
      }
    }
  }
}

// ---------------- LIF2 + maxpool -> p2h (f16 spikes, exact) ----------------
__global__ __launch_bounds__(256) void k_lif2pool(const float* __restrict__ h2,
                                                  f16* __restrict__ p2h) {
  int t = blockIdx.x * 256 + threadIdx.x;      // < 50176
  int px = t % 7;
  int r1 = t / 7;
  int py = r1 % 7;
  int r2 = r1 / 7;
  int c = r2 & 63, b = r2 >> 6;
  const float* base = h2 + ((size_t)b * 64 + c) * 196 + (2 * py) * 14 + 2 * px;
  const size_t tstride = (size_t)16 * 64 * 196;
  f16* op = p2h + (size_t)b * 3136 + c * 49 + py * 7 + px;
  const size_t otstride = (size_t)16 * 3136;
  float v00 = 0.f, v01 = 0.f, v10 = 0.f, v11 = 0.f;
#pragma unroll 4
  for (int tt = 0; tt < T_STEPS; ++tt) {
    const float* hp = base + (size_t)tt * tstride;
    float2 r0 = *(const float2*)(hp);
    float2 r1v = *(const float2*)(hp + 14);
    int s = 0;
    s |= lif_step_i(v00, r0.x);
    s |= lif_step_i(v01, r0.y);
    s |= lif_step_i(v10, r1v.x);
    s |= lif_step_i(v11, r1v.y);
    op[(size_t)tt * otstride] = (f16)s;
  }
}

// ---------------- FC1 via MFMA (fp16 hi/lo), split-K=2 -> two buffers, no atomics ----------
// grid 800 = 8 xcd * (4 slices * 25 tb-blocks). slice s=(yb,z); all 25 tb-blocks of a
// slice land on one XCD (bid%8 = s%8) -> weight slice (1.6MB) stays in that XCD's L2.
// Block: 64 tb x 64 o, 4 waves (wave = o-16-block). 1600/64 = 25 exactly: no tail guards.
__global__ __launch_bounds__(256, 4) void k_fc1(const f16* __restrict__ p2h,
                                                const f16* __restrict__ whi, const f16* __restrict__ wlo,
                                                float* __restrict__ h3a, float* __restrict__ h3b) {
  __shared__ unsigned char bsm[2][64 * 80];    // f16 [64 tb][32 k], row 80B (<=2-way conflict)
  const int tid = threadIdx.x;
  const int lane = tid & 63;
  const int wave = tid >> 6;
  int bid = blockIdx.x;
  int k8 = bid & 7, j = bid >> 3;              // j < 100
  int sh = j / 25, xb = j - sh * 25;           // sh<4, xb<25
  int s = k8 + 8 * sh;                         // slice < 32
  int yb = s >> 1, z = s & 1;
  const int tb0 = xb * 64;
  const int oblk = yb * 4 + wave;              // o-16-block
  const int tbl = tid >> 2, quarter = tid & 3; // staging role: 16B per thread
  const uint4* spq = (const uint4*)(p2h + (size_t)(tb0 + tbl) * 3136 + z * 1568 + quarter * 8);

  f32x4 accH[4], accL[4];
#pragma unroll
  for (int n = 0; n < 4; ++n) {
    accH[n] = (f32x4){0.f, 0.f, 0.f, 0.f};
    accL[n] = (f32x4){0.f, 0.f, 0.f, 0.f};
  }

  size_t afrag = ((size_t)((z * 49) * 64 + oblk) * 64 + lane) * 8;
  const size_t astep = (size_t)64 * 64 * 8;    // elements per kbG
  f16x8 ahC = *(const f16x8*)(whi + afrag);
  f16x8 alC = *(const f16x8*)(wlo + afrag);
  uint4 dC = spq[0];

  for (int kb = 0; kb < 49; ++kb) {
    // prefetch next iteration's B tile + A frags (hides global latency under MFMA)
    uint4 nC = dC;
    f16x8 ahN = ahC, alN = alC;
    if (kb < 48) {
      nC = spq[kb * 4 + 4];
      ahN = *(const f16x8*)(whi + afrag + (size_t)(kb + 1) * astep);
      alN = *(const f16x8*)(wlo + afrag + (size_t)(kb + 1) * astep);
    }
    *(uint4*)(&bsm[kb & 1][tbl * 80 + quarter * 16]) = dC;
    __syncthreads();
    const unsigned char* buf = &bsm[kb & 1][0];
#pragma unroll
    for (int n = 0; n < 4; ++n) {
      f16x8 bf = *(const f16x8*)(buf + (n * 16 + (lane & 15)) * 80 + (lane >> 4) * 16);
      accH[n] = __builtin_amdgcn_mfma_f32_16x16x32_f16(ahC, bf, accH[n], 0, 0, 0);
      accL[n] = __builtin_amdgcn_mfma_f32_16x16x32_f16(alC, bf, accL[n], 0, 0, 0);
    }
    dC = nC; ahC = ahN; alC = alN;
  }

  float* h3z = z ? h3b : h3a;
  const int o = yb * 64 + wave * 16 + (lane >> 4) * 4;
#pragma unroll
  for (int n = 0; n < 4; ++n) {
    int tb = tb0 + n * 16 + (lane & 15);
    float4 sv;
    sv.x = __fadd_rn(accH[n][0], __fmul_rn(accL[n][0], 1.0f / 4096.0f));
    sv.y = __fadd_rn(accH[n][1], __fmul_rn(accL[n][1], 1.0f / 4096.0f));
    sv.z = __fadd_rn(accH[n][2], __fmul_rn(accL[n][2], 1.0f / 4096.0f));
    sv.w = __fadd_rn(accH[n][3], __fmul_rn(accL[n][3], 1.0f / 4096.0f));
    *(float4*)(h3z + (size_t)tb * 1024 + o) = sv;
  }
}

// ---------------- LIF3 -> s3 (u8); x = h3a + h3b (deterministic single add) ----------------
__global__ __launch_bounds__(256) void k_lif3(const float* __restrict__ h3a,
                                              const float* __restrict__ h3b,
                                              unsigned char* __restrict__ s3) {
  int t = blockIdx.x * 256 + threadIdx.x;      // < 16384
  size_t base = (size_t)t;
  float v = 0.f;
#pragma unroll 10
  for (int tt = 0; tt < T_STEPS; ++tt) {
    size_t idx = base + (size_t)tt * 16384;
    float xv = __fadd_rn(h3a[idx], h3b[idx]);
    s3[idx] = (unsigned char)lif_step_i(v, xv);
  }
}

// ---------------- FC2 ----------------
__global__ __launch_bounds__(64) void k_fc2(const unsigned char* __restrict__ s3,
                                            const float* __restrict__ wfc2,
                                            float* __restrict__ h4) {
  int tb = blockIdx.x;                          // < 1600
  int l = threadIdx.x;
  const unsigned char* srow = s3 + (size_t)tb * 1024;
  float p[10];
#pragma unroll
  for (int o = 0; o < 10; ++o) p[o] = 0.f;
  for (int j = 0; j < 16; ++j) {
    int k = l + j * 64;
    float s = (float)srow[k];
#pragma unroll
    for (int o = 0; o < 10; ++o)
      p[o] = fmaf(s, wfc2[o * 1024 + k], p[o]);
  }
#pragma unroll
  for (int o = 0; o < 10; ++o) {
    float v = p[o];
    for (int off = 32; off > 0; off >>= 1) v += __shfl_down(v, off, 64);
    if (l == 0) h4[(size_t)tb * 10 + o] = v;
  }
}

// ---------------- LIF4 + mean ----------------
__global__ __launch_bounds__(256) void k_lif4mean(const float* __restrict__ h4,
                                                  float* __restrict__ out) {
  int t = threadIdx.x;
  if (t >= 160) return;
  int o = t % 10, b = t / 10;
  float v = 0.f;
  int cnt = 0;
#pragma unroll 10
  for (int tt = 0; tt < T_STEPS; ++tt) {
    float xv = h4[(size_t)tt * 160 + b * 10 + o];
    cnt += lif_step_i(v, xv);
  }
  out[b * 10 + o] = (float)cnt / 100.0f;
}

extern "C" void kernel_launch(void* const* d_in, const int* in_sizes, int n_in,
                              void* d_out, int out_size, void* d_ws, size_t ws_size,
                              hipStream_t stream) {
  const float* x    = (const float*)d_in[0];
  const float* W1   = (const float*)d_in[1];
  const float* g1   = (const float*)d_in[2];
  const float* b1   = (const float*)d_in[3];
  const float* m1   = (const float*)d_in[4];
  const float* v1   = (const float*)d_in[5];
  const float* W2   = (const float*)d_in[6];
  const float* g2   = (const float*)d_in[7];
  const float* b2   = (const float*)d_in[8];
  const float* m2   = (const float*)d_in[9];
  const float* v2   = (const float*)d_in[10];
  const float* Wfc1 = (const float*)d_in[11];
  const float* Wfc2 = (const float*)d_in[12];
  float* out = (float*)d_out;
  char* ws = (char*)d_ws;

  float*         h1   = (float*)(ws + OFF_H1);
  f16*           whi  = (f16*)(ws + OFF_WHI);
  f16*           wlo  = (f16*)(ws + OFF_WLO);
  unsigned char* p1   = (unsigned char*)(ws + OFF_P1);
  float*         h2   = (float*)(ws + OFF_H2);
  f16*           p2h  = (f16*)(ws + OFF_P2H);
  float*         h3a  = (float*)(ws + OFF_H3A);
  float*         h3b  = (float*)(ws + OFF_H3B);
  unsigned char* s3   = (unsigned char*)(ws + OFF_S3);
  float*         h4   = (float*)(ws + OFF_H4);
  f16*           wf1h = (f16*)(ws + OFF_WF1H);
  f16*           wf1l = (f16*)(ws + OFF_WF1L);

  k_conv1<<<3136, 256, 0, stream>>>(x, W1, g1, b1, m1, v1, h1);
  k_lif1pool<<<1024, 256, 0, stream>>>(h1, p1);
  k_prep_w2<<<144, 256, 0, stream>>>(W2, whi, wlo);        // overlays dead h1
  k_conv2<<<1600, 256, 0, stream>>>(p1, whi, wlo, g2, b2, m2, v2, h2);
  k_lif2pool<<<196, 256, 0, stream>>>(h2, p2h);
  k_prep_wfc1<<<12544, 256, 0, stream>>>(Wfc1, wf1h, wf1l); // overlays dead h2
  k_fc1<<<800, 256, 0, stream>>>(p2h, wf1h, wf1l, h3a, h3b);
  k_lif3<<<64, 256, 0, stream>>>(h3a, h3b, s3);
  k_fc2<<<1600, 64, 0, stream>>>(s3, Wfc2, h4);
  k_lif4mean<<<1, 256, 0, stream>>>(h4, out);
}